// Round 1
// 4839.978 us; speedup vs baseline: 1.4214x; 1.4214x over previous
//
#include <hip/hip_runtime.h>

// ---------------------------------------------------------------------------
// RNN_13013750907457: T=256,B=64,V=10000,H=1024,O=10000
//   e = emb[x]; p = e@W_proj + b_proj
//   scan: gates = p_t@W_x + h@W_h + b_lstm -> i,f,g,o -> c,h
//   out = res@W_out + b_out ; returns (out, h_f, c_f)  (all f32)
// Strategy: fold W_proj@W_x -> Wc (xg = e@Wc + bc), bf16 MFMA GEMMs
// (m97 structure), persistent 256-block scan.
// R2: scan sync rewritten from global 256-block atomic-counter barrier to
// group-local (64-block) dataflow flags:
//   - h history lives in res (one slot per step, slot 0 = h0): no WAR hazard,
//     no anti-dependency barrier.
//   - producer: write-through (agent-scope) packed u32 h stores, then
//     release-store prog[bid] = t+1 (per-block flag, no RMW contention).
//   - consumer: wave 0 polls its 64 group peers' flags one-per-lane
//     (coalesced) with acquire loads; groups drift independently.
// ---------------------------------------------------------------------------

typedef __bf16 bf16x8 __attribute__((ext_vector_type(8)));
typedef float  f32x4  __attribute__((ext_vector_type(4)));

__device__ __forceinline__ unsigned short f2b(float f) {
    unsigned u = __builtin_bit_cast(unsigned, f);
    unsigned r = (u + 0x7fffu + ((u >> 16) & 1u)) >> 16;
    return (unsigned short)r;
}
__device__ __forceinline__ float b2f(unsigned short h) {
    return __builtin_bit_cast(float, ((unsigned)h) << 16);
}
__device__ __forceinline__ void gload16(const void* g, void* l) {
    __builtin_amdgcn_global_load_lds(
        (const __attribute__((address_space(1))) void*)g,
        (__attribute__((address_space(3))) void*)l, 16, 0, 0);
}
__device__ __forceinline__ float tanh_fast(float x) {
    x = fminf(fmaxf(x, -15.f), 15.f);
    float e = __expf(2.f * x);
    return (e - 1.f) / (e + 1.f);
}
__device__ __forceinline__ float sigmoid_fast(float x) {
    return 1.f / (1.f + __expf(-x));
}

// ----------------------------- converters ----------------------------------

__global__ void cvt_bf16(const float* __restrict__ in, unsigned short* __restrict__ out, int n) {
    int i = blockIdx.x * 256 + threadIdx.x;
    if (i < n) out[i] = f2b(in[i]);
}

// in f32 [R][C] -> out bf16 [C][R]
__global__ void transpose_cvt(const float* __restrict__ in, unsigned short* __restrict__ out,
                              int R, int C) {
    __shared__ float tile[64][65];
    int c0 = blockIdx.x * 64, r0 = blockIdx.y * 64;
    int tx = threadIdx.x & 63, ty = threadIdx.x >> 6;
#pragma unroll
    for (int i = 0; i < 16; ++i) {
        int r = ty * 16 + i;
        int gc = c0 + tx;
        tile[r][tx] = (gc < C) ? in[(size_t)(r0 + r) * C + gc] : 0.f;
    }
    __syncthreads();
#pragma unroll
    for (int i = 0; i < 16; ++i) {
        int cc = ty * 16 + i;
        int gc = c0 + cc;
        if (gc < C) out[(size_t)gc * R + r0 + tx] = f2b(tile[tx][cc]);
    }
}

// W_h (1024x4096 f32) -> frag-order bf16: [ng(64)][gate(4)][kk(32)][lane(64)][8]
// element = W_h[kk*32 + (lane>>4)*8 + j][gate*1024 + ng*16 + (lane&15)]
__global__ void whf_build(const float* __restrict__ Wh, unsigned short* __restrict__ Whf) {
    int t = blockIdx.x * 256 + threadIdx.x;   // 524288 total
    int lane = t & 63, kk = (t >> 6) & 31, w = (t >> 11) & 3, ng = t >> 13;
    int q = lane >> 4, cl = lane & 15;
    int col = w * 1024 + ng * 16 + cl;
    size_t ob = (size_t)t * 8;
#pragma unroll
    for (int j = 0; j < 8; ++j) {
        int k = kk * 32 + q * 8 + j;
        Whf[ob + j] = f2b(Wh[(size_t)k * 4096 + col]);
    }
}

// bc[n] = b_lstm[n] + sum_k b_proj[k]*W_x[k][n]
__global__ void bc_build(const float* __restrict__ bproj, const float* __restrict__ Wx,
                         const float* __restrict__ blstm, float* __restrict__ bc) {
    int n = blockIdx.x * 256 + threadIdx.x;   // 4096
    float s = blstm[n];
    for (int k = 0; k < 1024; ++k) s += bproj[k] * Wx[(size_t)k * 4096 + n];
    bc[n] = s;
}

// ------------------------------- GEMM --------------------------------------
// C[M][N] = A[M][K=1024] @ Bt[N][K]^T + bias, bf16 in, f32 accum.
// MODE 0: f32 C at row*ldc+col; 1: bf16 C; 2: bf16 C transposed (col*ldc+row).
// GATHER: A row m comes from A[gidx[m]].
template <int MODE, bool GATHER>
__global__ void __launch_bounds__(256) gemm_bt(
    const unsigned short* __restrict__ A, const unsigned short* __restrict__ Bt,
    const int* __restrict__ gidx, const float* __restrict__ bias,
    void* __restrict__ Cv, int M, int N, long ldc)
{
    __shared__ unsigned short As[128 * 32];   // 8 KB, [m][k]
    __shared__ unsigned short Bs[128 * 32];   // 8 KB, [n][k]
    const int tid = threadIdx.x;
    const int lane = tid & 63, wv = tid >> 6;
    const int q = lane >> 4, cl = lane & 15;
    const int wr = wv >> 1, wc = wv & 1;
    const long m0 = (long)blockIdx.y * 128;
    const long n0 = (long)blockIdx.x * 128;

    const unsigned short* aptr[2];
    const unsigned short* bptr[2];
#pragma unroll
    for (int r = 0; r < 2; ++r) {
        int c = r * 256 + tid;
        int row = c >> 2;
        int co = (c & 3) * 8;
        long am = m0 + row;
        long arow = GATHER ? (long)gidx[am] : am;
        aptr[r] = A + arow * 1024 + co;
        long bn = n0 + row; if (bn > N - 1) bn = N - 1;
        bptr[r] = Bt + bn * 1024 + co;
    }

    f32x4 zero = {0.f, 0.f, 0.f, 0.f};
    f32x4 acc[4][4];
#pragma unroll
    for (int i = 0; i < 4; ++i)
#pragma unroll
        for (int j = 0; j < 4; ++j) acc[i][j] = zero;

    char* AsB = (char*)As;
    char* BsB = (char*)Bs;
    for (int kt = 0; kt < 1024; kt += 32) {
        __syncthreads();
#pragma unroll
        for (int r = 0; r < 2; ++r) {
            gload16(aptr[r] + kt, AsB + r * 4096 + wv * 1024);
            gload16(bptr[r] + kt, BsB + r * 4096 + wv * 1024);
        }
        __syncthreads();
        bf16x8 af[4], bf[4];
#pragma unroll
        for (int mt = 0; mt < 4; ++mt)
            af[mt] = *(const bf16x8*)(As + (wr * 64 + mt * 16 + cl) * 32 + q * 8);
#pragma unroll
        for (int nt = 0; nt < 4; ++nt)
            bf[nt] = *(const bf16x8*)(Bs + (wc * 64 + nt * 16 + cl) * 32 + q * 8);
#pragma unroll
        for (int mt = 0; mt < 4; ++mt)
#pragma unroll
            for (int nt = 0; nt < 4; ++nt)
                acc[mt][nt] = __builtin_amdgcn_mfma_f32_16x16x32_bf16(
                    af[mt], bf[nt], acc[mt][nt], 0, 0, 0);
    }

#pragma unroll
    for (int nt = 0; nt < 4; ++nt) {
        long col = n0 + wc * 64 + nt * 16 + cl;
        long bcol = (col < N) ? col : (N - 1);
        float bv = bias ? bias[bcol] : 0.f;
#pragma unroll
        for (int mt = 0; mt < 4; ++mt) {
            long row = m0 + wr * 64 + mt * 16 + q * 4;
#pragma unroll
            for (int g = 0; g < 4; ++g) {
                float v = acc[mt][nt][g] + bv;
                if (col < N) {
                    if (MODE == 0)      ((float*)Cv)[(row + g) * ldc + col] = v;
                    else if (MODE == 1) ((unsigned short*)Cv)[(row + g) * ldc + col] = f2b(v);
                    else                ((unsigned short*)Cv)[col * ldc + (row + g)] = f2b(v);
                }
            }
        }
    }
}

// ------------------------------- scan --------------------------------------
// 256 blocks (1/CU) x 256 thr. bid = mg*64 + ng: mg selects 16 batch rows,
// ng selects 16 h-cols. Wave w = gate w; W_h slice in LDS in B-frag order.
// h history in R: R slot s holds h_{s-1} (slot 0 = h0); step t reads R[t],
// writes R[t+1]. Sync = per-group-of-64 dataflow flags (prog[bid] = steps
// completed), release/acquire agent-scope atomics. No global barrier.
__global__ void __launch_bounds__(256) lstm_scan(
    const unsigned short* __restrict__ Whf, const unsigned short* __restrict__ xg,
    const float* __restrict__ cinit, unsigned short* __restrict__ R,
    float* __restrict__ hf_out, float* __restrict__ cf_out,
    unsigned int* __restrict__ prog)
{
    __shared__ unsigned short Whs[65536];     // 128 KB
    __shared__ float gx[4][16][16];           // 4 KB gate exchange
    const int tid = threadIdx.x;
    const int lane = tid & 63, w = tid >> 6;
    const int q = lane >> 4, cl = lane & 15;
    const int mg = blockIdx.x >> 6, ng = blockIdx.x & 63;
    const int m0 = mg * 16, j0 = ng * 16;

    // stage W_h slice (identical linear layout in global and LDS)
    const unsigned short* slice = Whf + (size_t)ng * 65536;
    char* WhsB = (char*)Whs;
#pragma unroll
    for (int r = 0; r < 32; ++r)
        gload16(slice + (r * 256 + tid) * 8, WhsB + (r * 256 + w * 64) * 16);

    const int er = tid >> 4, ec = tid & 15;
    const int be = m0 + er, je = j0 + ec;
    float creg = cinit[be * 1024 + je];
    __syncthreads();

    const unsigned short* bfrag = Whs + w * 16384 + lane * 8;
    unsigned int* myflag = prog + blockIdx.x;
    const unsigned int* gflags = prog + mg * 64;   // my 64 producers

    for (int t = 0; t < 256; ++t) {
        // xg loads are flag-independent: issue before the wait to overlap it
        const unsigned short* xgt = xg + ((size_t)(t * 64 + be)) * 4096 + je;
        unsigned short xi = xgt[0], xf = xgt[1024], xg2 = xgt[2048], xo = xgt[3072];

        // wait for all 64 group peers to have produced R[t] (step t-1 done)
        if (t > 0) {
            if (tid < 64) {
                const unsigned tgt = (unsigned)t;
                for (;;) {
                    unsigned v = __hip_atomic_load(gflags + tid, __ATOMIC_ACQUIRE,
                                                   __HIP_MEMORY_SCOPE_AGENT);
                    if (__all((int)(v >= tgt))) break;
                    __builtin_amdgcn_s_sleep(2);
                }
            }
            __syncthreads();
        }

        // gates = h_{t-1} @ Whs  (2 accumulators to halve the dep chain)
        const unsigned short* hb = R + ((size_t)(t * 64) + m0 + cl) * 1024 + q * 8;
        f32x4 acc0 = {0.f, 0.f, 0.f, 0.f};
        f32x4 acc1 = {0.f, 0.f, 0.f, 0.f};
#pragma unroll
        for (int kk = 0; kk < 32; kk += 2) {
            bf16x8 a0 = *(const bf16x8*)(hb + kk * 32);
            bf16x8 b0 = *(const bf16x8*)(bfrag + kk * 512);
            acc0 = __builtin_amdgcn_mfma_f32_16x16x32_bf16(a0, b0, acc0, 0, 0, 0);
            bf16x8 a1 = *(const bf16x8*)(hb + (kk + 1) * 32);
            bf16x8 b1 = *(const bf16x8*)(bfrag + (kk + 1) * 512);
            acc1 = __builtin_amdgcn_mfma_f32_16x16x32_bf16(a1, b1, acc1, 0, 0, 0);
        }
#pragma unroll
        for (int g = 0; g < 4; ++g) gx[w][q * 4 + g][cl] = acc0[g] + acc1[g];
        __syncthreads();

        float Gi = gx[0][er][ec] + b2f(xi);
        float Gf = gx[1][er][ec] + b2f(xf);
        float Gg = gx[2][er][ec] + b2f(xg2);
        float Go = gx[3][er][ec] + b2f(xo);
        float iv = sigmoid_fast(Gi), fv = sigmoid_fast(Gf), ov = sigmoid_fast(Go);
        float gv = tanh_fast(Gg);
        creg = fv * creg + iv * gv;
        float hn = ov * tanh_fast(creg);
        unsigned short h16 = f2b(hn);

        // pack 2 bf16 -> u32, write-through (agent scope) so the release
        // flag store has no dirty L2 to flush
        unsigned up = (unsigned)h16;
        unsigned nb = (unsigned)__shfl_down((int)up, 1);
        if ((ec & 1) == 0) {
            unsigned pack = up | (nb << 16);
            __hip_atomic_store(
                (unsigned*)(R + ((size_t)((t + 1) * 64) + be) * 1024 + je),
                pack, __ATOMIC_RELAXED, __HIP_MEMORY_SCOPE_AGENT);
        }
        if (t == 255) { hf_out[be * 1024 + je] = hn; cf_out[be * 1024 + je] = creg; }

        __syncthreads();   // drains each wave's vmcnt -> block's stores visible
        if (tid == 0)
            __hip_atomic_store(myflag, (unsigned)(t + 1), __ATOMIC_RELEASE,
                               __HIP_MEMORY_SCOPE_AGENT);
    }
}

// ------------------------------ launcher -----------------------------------

extern "C" void kernel_launch(void* const* d_in, const int* in_sizes, int n_in,
                              void* d_out, int out_size, void* d_ws, size_t ws_size,
                              hipStream_t stream) {
    const int*   x     = (const int*)d_in[0];
    const float* h0    = (const float*)d_in[1];
    const float* c0    = (const float*)d_in[2];
    const float* emb   = (const float*)d_in[3];
    const float* Wproj = (const float*)d_in[4];
    const float* bproj = (const float*)d_in[5];
    const float* Wx    = (const float*)d_in[6];
    const float* Wh    = (const float*)d_in[7];
    const float* blstm = (const float*)d_in[8];
    const float* Wout  = (const float*)d_in[9];
    const float* bout  = (const float*)d_in[10];
    float* out = (float*)d_out;

    char* ws = (char*)d_ws;
    // 256-aligned offsets (total ~236.1 MB)
    const size_t OFF_EMB = 256;          // 20,480,000 B (emb bf16)
    const size_t OFF_WP  = 20480256;     //  2,097,152 B (W_proj bf16)
    const size_t OFF_WXT = 22577408;     //  8,388,608 B (W_x^T bf16, 4096x1024)
    const size_t OFF_WCT = 30966016;     //  8,388,608 B (Wc^T bf16, 4096x1024)
    const size_t OFF_WHF = 39354624;     //  8,388,608 B (W_h frag-order bf16)
    const size_t OFF_WOT = 47743232;     // 20,480,000 B (W_out^T bf16, 10000x1024)
    const size_t OFF_BC  = 68223232;     //     16,384 B (bc f32)
    const size_t OFF_XG  = 68239616;     // 134,217,728 B (xg bf16, 16384x4096)
    const size_t OFF_RES = 202457344;    // 33,685,504 B (h history bf16, 257x64x1024)
    const size_t OFF_PROG= 236142848;    //      1,024 B (progress flags)

    unsigned short* emb_bf = (unsigned short*)(ws + OFF_EMB);
    unsigned short* Wp_bf  = (unsigned short*)(ws + OFF_WP);
    unsigned short* WxT    = (unsigned short*)(ws + OFF_WXT);
    unsigned short* WcT    = (unsigned short*)(ws + OFF_WCT);
    unsigned short* Whf    = (unsigned short*)(ws + OFF_WHF);
    unsigned short* WoT    = (unsigned short*)(ws + OFF_WOT);
    float*          bc     = (float*)(ws + OFF_BC);
    unsigned short* xg     = (unsigned short*)(ws + OFF_XG);
    unsigned short* resb   = (unsigned short*)(ws + OFF_RES);  // slot 0 = h0
    unsigned int*   prog   = (unsigned int*)(ws + OFF_PROG);

    hipMemsetAsync(prog, 0, 1024, stream);

    cvt_bf16<<<40000, 256, 0, stream>>>(emb, emb_bf, 10240000);
    cvt_bf16<<<4096, 256, 0, stream>>>(Wproj, Wp_bf, 1048576);
    cvt_bf16<<<256, 256, 0, stream>>>(h0, resb, 65536);          // h0 -> slot 0
    transpose_cvt<<<dim3(64, 16), 256, 0, stream>>>(Wx, WxT, 1024, 4096);
    transpose_cvt<<<dim3(157, 16), 256, 0, stream>>>(Wout, WoT, 1024, 10000);
    whf_build<<<2048, 256, 0, stream>>>(Wh, Whf);
    bc_build<<<16, 256, 0, stream>>>(bproj, Wx, blstm, bc);

    // Wc^T = (W_proj @ W_x)^T   (bf16, transposed store)
    gemm_bt<2, false><<<dim3(32, 8), 256, 0, stream>>>(
        Wp_bf, WxT, (const int*)nullptr, (const float*)nullptr, WcT, 1024, 4096, 1024);

    // xg = emb[x] @ Wc + bc   (bf16 out)
    gemm_bt<1, true><<<dim3(32, 128), 256, 0, stream>>>(
        emb_bf, WcT, x, bc, xg, 16384, 4096, 4096);

    // sequential LSTM scan (persistent, 1 block/CU, dataflow flags)
    lstm_scan<<<256, 256, 0, stream>>>(Whf, xg, c0, resb,
                                       out + 163840000, out + 163905536, prog);

    // out = res @ W_out + b_out  (f32 to d_out; skip h0 slot)
    gemm_bt<0, false><<<dim3(79, 128), 256, 0, stream>>>(
        resb + 65536, WoT, (const int*)nullptr, bout, d_out, 16384, 10000, 10000);
}

// Round 2
// 2418.199 us; speedup vs baseline: 2.8449x; 2.0015x over previous
//
#include <hip/hip_runtime.h>

// ---------------------------------------------------------------------------
// RNN_13013750907457: T=256,B=64,V=10000,H=1024,O=10000
//   e = emb[x]; p = e@W_proj + b_proj
//   scan: gates = p_t@W_x + h@W_h + b_lstm -> i,f,g,o -> c,h
//   out = res@W_out + b_out ; returns (out, h_f, c_f)  (all f32)
// Strategy: fold W_proj@W_x -> Wc (xg = e@Wc + bc), bf16 MFMA GEMMs
// (m97 structure), persistent 256-block scan with group-local (64-block)
// dataflow flags.
// R3: remove ALL cache-maintenance ops from the scan steady state:
//   - h exchange buffer X[t][mg][ng][16][16]: each producer owns an
//     exclusive line-aligned 512B region -> no false sharing -> no
//     buffer_inv needed on the consumer side.
//   - flags and h stores are RELAXED sc1 (write-through) ops; ordering
//     comes from the vmcnt(0) drain inside __syncthreads -> no release
//     buffer_wbl2 per step.
//   - res (GEMM layout) written off the critical path after the flag.
// ---------------------------------------------------------------------------

typedef __bf16 bf16x8 __attribute__((ext_vector_type(8)));
typedef float  f32x4  __attribute__((ext_vector_type(4)));

__device__ __forceinline__ unsigned short f2b(float f) {
    unsigned u = __builtin_bit_cast(unsigned, f);
    unsigned r = (u + 0x7fffu + ((u >> 16) & 1u)) >> 16;
    return (unsigned short)r;
}
__device__ __forceinline__ float b2f(unsigned short h) {
    return __builtin_bit_cast(float, ((unsigned)h) << 16);
}
__device__ __forceinline__ void gload16(const void* g, void* l) {
    __builtin_amdgcn_global_load_lds(
        (const __attribute__((address_space(1))) void*)g,
        (__attribute__((address_space(3))) void*)l, 16, 0, 0);
}
__device__ __forceinline__ float tanh_fast(float x) {
    x = fminf(fmaxf(x, -15.f), 15.f);
    float e = __expf(2.f * x);
    return (e - 1.f) / (e + 1.f);
}
__device__ __forceinline__ float sigmoid_fast(float x) {
    return 1.f / (1.f + __expf(-x));
}

// ----------------------------- converters ----------------------------------

__global__ void cvt_bf16(const float* __restrict__ in, unsigned short* __restrict__ out, int n) {
    int i = blockIdx.x * 256 + threadIdx.x;
    if (i < n) out[i] = f2b(in[i]);
}

// h0 f32 [64][1024] -> X slot 0 in exchange layout [mg][ng][er][ec]
__global__ void seed_h0(const float* __restrict__ h0, unsigned short* __restrict__ X) {
    int i = blockIdx.x * 256 + threadIdx.x;    // 65536
    int b = i >> 10, j = i & 1023;
    int off = (b >> 4) * 16384 + (j >> 4) * 256 + (b & 15) * 16 + (j & 15);
    X[off] = f2b(h0[i]);
}

// in f32 [R][C] -> out bf16 [C][R]
__global__ void transpose_cvt(const float* __restrict__ in, unsigned short* __restrict__ out,
                              int R, int C) {
    __shared__ float tile[64][65];
    int c0 = blockIdx.x * 64, r0 = blockIdx.y * 64;
    int tx = threadIdx.x & 63, ty = threadIdx.x >> 6;
#pragma unroll
    for (int i = 0; i < 16; ++i) {
        int r = ty * 16 + i;
        int gc = c0 + tx;
        tile[r][tx] = (gc < C) ? in[(size_t)(r0 + r) * C + gc] : 0.f;
    }
    __syncthreads();
#pragma unroll
    for (int i = 0; i < 16; ++i) {
        int cc = ty * 16 + i;
        int gc = c0 + cc;
        if (gc < C) out[(size_t)gc * R + r0 + tx] = f2b(tile[tx][cc]);
    }
}

// W_h (1024x4096 f32) -> frag-order bf16: [ng(64)][gate(4)][kk(32)][lane(64)][8]
// element = W_h[kk*32 + (lane>>4)*8 + j][gate*1024 + ng*16 + (lane&15)]
__global__ void whf_build(const float* __restrict__ Wh, unsigned short* __restrict__ Whf) {
    int t = blockIdx.x * 256 + threadIdx.x;   // 524288 total
    int lane = t & 63, kk = (t >> 6) & 31, w = (t >> 11) & 3, ng = t >> 13;
    int q = lane >> 4, cl = lane & 15;
    int col = w * 1024 + ng * 16 + cl;
    size_t ob = (size_t)t * 8;
#pragma unroll
    for (int j = 0; j < 8; ++j) {
        int k = kk * 32 + q * 8 + j;
        Whf[ob + j] = f2b(Wh[(size_t)k * 4096 + col]);
    }
}

// bc[n] = b_lstm[n] + sum_k b_proj[k]*W_x[k][n]
__global__ void bc_build(const float* __restrict__ bproj, const float* __restrict__ Wx,
                         const float* __restrict__ blstm, float* __restrict__ bc) {
    int n = blockIdx.x * 256 + threadIdx.x;   // 4096
    float s = blstm[n];
    for (int k = 0; k < 1024; ++k) s += bproj[k] * Wx[(size_t)k * 4096 + n];
    bc[n] = s;
}

// ------------------------------- GEMM --------------------------------------
// C[M][N] = A[M][K=1024] @ Bt[N][K]^T + bias, bf16 in, f32 accum.
// MODE 0: f32 C at row*ldc+col; 1: bf16 C; 2: bf16 C transposed (col*ldc+row).
// GATHER: A row m comes from A[gidx[m]].
template <int MODE, bool GATHER>
__global__ void __launch_bounds__(256) gemm_bt(
    const unsigned short* __restrict__ A, const unsigned short* __restrict__ Bt,
    const int* __restrict__ gidx, const float* __restrict__ bias,
    void* __restrict__ Cv, int M, int N, long ldc)
{
    __shared__ unsigned short As[128 * 32];   // 8 KB, [m][k]
    __shared__ unsigned short Bs[128 * 32];   // 8 KB, [n][k]
    const int tid = threadIdx.x;
    const int lane = tid & 63, wv = tid >> 6;
    const int q = lane >> 4, cl = lane & 15;
    const int wr = wv >> 1, wc = wv & 1;
    const long m0 = (long)blockIdx.y * 128;
    const long n0 = (long)blockIdx.x * 128;

    const unsigned short* aptr[2];
    const unsigned short* bptr[2];
#pragma unroll
    for (int r = 0; r < 2; ++r) {
        int c = r * 256 + tid;
        int row = c >> 2;
        int co = (c & 3) * 8;
        long am = m0 + row;
        long arow = GATHER ? (long)gidx[am] : am;
        aptr[r] = A + arow * 1024 + co;
        long bn = n0 + row; if (bn > N - 1) bn = N - 1;
        bptr[r] = Bt + bn * 1024 + co;
    }

    f32x4 zero = {0.f, 0.f, 0.f, 0.f};
    f32x4 acc[4][4];
#pragma unroll
    for (int i = 0; i < 4; ++i)
#pragma unroll
        for (int j = 0; j < 4; ++j) acc[i][j] = zero;

    char* AsB = (char*)As;
    char* BsB = (char*)Bs;
    for (int kt = 0; kt < 1024; kt += 32) {
        __syncthreads();
#pragma unroll
        for (int r = 0; r < 2; ++r) {
            gload16(aptr[r] + kt, AsB + r * 4096 + wv * 1024);
            gload16(bptr[r] + kt, BsB + r * 4096 + wv * 1024);
        }
        __syncthreads();
        bf16x8 af[4], bf[4];
#pragma unroll
        for (int mt = 0; mt < 4; ++mt)
            af[mt] = *(const bf16x8*)(As + (wr * 64 + mt * 16 + cl) * 32 + q * 8);
#pragma unroll
        for (int nt = 0; nt < 4; ++nt)
            bf[nt] = *(const bf16x8*)(Bs + (wc * 64 + nt * 16 + cl) * 32 + q * 8);
#pragma unroll
        for (int mt = 0; mt < 4; ++mt)
#pragma unroll
            for (int nt = 0; nt < 4; ++nt)
                acc[mt][nt] = __builtin_amdgcn_mfma_f32_16x16x32_bf16(
                    af[mt], bf[nt], acc[mt][nt], 0, 0, 0);
    }

#pragma unroll
    for (int nt = 0; nt < 4; ++nt) {
        long col = n0 + wc * 64 + nt * 16 + cl;
        long bcol = (col < N) ? col : (N - 1);
        float bv = bias ? bias[bcol] : 0.f;
#pragma unroll
        for (int mt = 0; mt < 4; ++mt) {
            long row = m0 + wr * 64 + mt * 16 + q * 4;
#pragma unroll
            for (int g = 0; g < 4; ++g) {
                float v = acc[mt][nt][g] + bv;
                if (col < N) {
                    if (MODE == 0)      ((float*)Cv)[(row + g) * ldc + col] = v;
                    else if (MODE == 1) ((unsigned short*)Cv)[(row + g) * ldc + col] = f2b(v);
                    else                ((unsigned short*)Cv)[col * ldc + (row + g)] = f2b(v);
                }
            }
        }
    }
}

// ------------------------------- scan --------------------------------------
// 256 blocks (1/CU) x 256 thr. bid = mg*64 + ng: mg selects 16 batch rows,
// ng selects 16 h-cols. Wave w = gate w; W_h slice in LDS in B-frag order.
// h history in exchange layout X[t][mg][ng][er][ec] (slot 0 = h0): producer
// (mg,ng) owns an exclusive 512B region per slot -> no false sharing -> no
// cache invalidation needed. All cross-block stores/loads are RELAXED sc1;
// ordering by the vmcnt(0) drain of __syncthreads before the flag store.
__global__ void __launch_bounds__(256) lstm_scan(
    const unsigned short* __restrict__ Whf, const unsigned short* __restrict__ xg,
    const float* __restrict__ cinit, unsigned short* __restrict__ X,
    unsigned short* __restrict__ res, float* __restrict__ hf_out,
    float* __restrict__ cf_out, unsigned int* __restrict__ prog)
{
    __shared__ unsigned short Whs[65536];     // 128 KB
    __shared__ float gx[4][16][16];           // 4 KB gate exchange
    const int tid = threadIdx.x;
    const int lane = tid & 63, w = tid >> 6;
    const int q = lane >> 4, cl = lane & 15;
    const int mg = blockIdx.x >> 6, ng = blockIdx.x & 63;
    const int m0 = mg * 16, j0 = ng * 16;

    // stage W_h slice (identical linear layout in global and LDS)
    const unsigned short* slice = Whf + (size_t)ng * 65536;
    char* WhsB = (char*)Whs;
#pragma unroll
    for (int r = 0; r < 32; ++r)
        gload16(slice + (r * 256 + tid) * 8, WhsB + (r * 256 + w * 64) * 16);

    const int er = tid >> 4, ec = tid & 15;
    const int be = m0 + er, je = j0 + ec;
    float creg = cinit[be * 1024 + je];
    __syncthreads();

    const unsigned short* bfrag = Whs + w * 16384 + lane * 8;
    unsigned int* myflag = prog + blockIdx.x;
    const unsigned int* gflags = prog + mg * 64;   // my 64 producers
    // A-fragment base inside a slot: k = kk*32 + q*8 + j ->
    //   region ng_src = 2*kk + (q>>1), col (q&1)*8 + j, row cl
    const unsigned base_a = (unsigned)(mg * 16384 + (q >> 1) * 256 + cl * 16 + (q & 1) * 8);
    const unsigned base_w = (unsigned)(mg * 16384 + ng * 256 + er * 16 + ec);

    for (int t = 0; t < 256; ++t) {
        // xg loads are flag-independent: issue before the wait to overlap it
        const unsigned short* xgt = xg + ((size_t)(t * 64 + be)) * 4096 + je;
        unsigned short xi = xgt[0], xf = xgt[1024], xg2 = xgt[2048], xo = xgt[3072];

        // wait for all 64 group peers to have produced X[t] (step t-1 done)
        if (t > 0) {
            if (tid < 64) {
                const unsigned tgt = (unsigned)t;
                for (;;) {
                    unsigned v = __hip_atomic_load(gflags + tid, __ATOMIC_RELAXED,
                                                   __HIP_MEMORY_SCOPE_AGENT);
                    if (__all((int)(v >= tgt))) break;
                    __builtin_amdgcn_s_sleep(1);
                }
            }
            __syncthreads();   // also a compiler fence: h loads stay below
        }

        // gates = h_{t-1} @ Whs  (2 accumulators to halve the dep chain)
        const unsigned short* hb = X + (size_t)t * 65536 + base_a;
        f32x4 acc0 = {0.f, 0.f, 0.f, 0.f};
        f32x4 acc1 = {0.f, 0.f, 0.f, 0.f};
#pragma unroll
        for (int kk = 0; kk < 32; kk += 2) {
            bf16x8 a0 = *(const bf16x8*)(hb + kk * 512);
            bf16x8 b0 = *(const bf16x8*)(bfrag + kk * 512);
            acc0 = __builtin_amdgcn_mfma_f32_16x16x32_bf16(a0, b0, acc0, 0, 0, 0);
            bf16x8 a1 = *(const bf16x8*)(hb + (kk + 1) * 512);
            bf16x8 b1 = *(const bf16x8*)(bfrag + (kk + 1) * 512);
            acc1 = __builtin_amdgcn_mfma_f32_16x16x32_bf16(a1, b1, acc1, 0, 0, 0);
        }
#pragma unroll
        for (int g = 0; g < 4; ++g) gx[w][q * 4 + g][cl] = acc0[g] + acc1[g];
        __syncthreads();

        float Gi = gx[0][er][ec] + b2f(xi);
        float Gf = gx[1][er][ec] + b2f(xf);
        float Gg = gx[2][er][ec] + b2f(xg2);
        float Go = gx[3][er][ec] + b2f(xo);
        float iv = sigmoid_fast(Gi), fv = sigmoid_fast(Gf), ov = sigmoid_fast(Go);
        float gv = tanh_fast(Gg);
        creg = fv * creg + iv * gv;
        float hn = ov * tanh_fast(creg);
        unsigned short h16 = f2b(hn);

        // pack 2 bf16 -> u32, write-through (sc1) to exchange buffer
        unsigned up = (unsigned)h16;
        unsigned nb = (unsigned)__shfl_down((int)up, 1);
        unsigned pack = up | (nb << 16);
        if ((ec & 1) == 0)
            __hip_atomic_store((unsigned*)(X + (size_t)(t + 1) * 65536 + base_w),
                               pack, __ATOMIC_RELAXED, __HIP_MEMORY_SCOPE_AGENT);
        if (t == 255) { hf_out[be * 1024 + je] = hn; cf_out[be * 1024 + je] = creg; }

        __syncthreads();   // all waves vmcnt(0): X stores at coherence point
        if (tid == 0)
            __hip_atomic_store(myflag, (unsigned)(t + 1), __ATOMIC_RELAXED,
                               __HIP_MEMORY_SCOPE_AGENT);

        // res in GEMM layout — off the critical path, normal (write-back) store
        if ((ec & 1) == 0)
            *(unsigned*)(res + ((size_t)(t * 64 + be)) * 1024 + je) = pack;
    }
}

// ------------------------------ launcher -----------------------------------

extern "C" void kernel_launch(void* const* d_in, const int* in_sizes, int n_in,
                              void* d_out, int out_size, void* d_ws, size_t ws_size,
                              hipStream_t stream) {
    const int*   x     = (const int*)d_in[0];
    const float* h0    = (const float*)d_in[1];
    const float* c0    = (const float*)d_in[2];
    const float* emb   = (const float*)d_in[3];
    const float* Wproj = (const float*)d_in[4];
    const float* bproj = (const float*)d_in[5];
    const float* Wx    = (const float*)d_in[6];
    const float* Wh    = (const float*)d_in[7];
    const float* blstm = (const float*)d_in[8];
    const float* Wout  = (const float*)d_in[9];
    const float* bout  = (const float*)d_in[10];
    float* out = (float*)d_out;

    char* ws = (char*)d_ws;
    // 256-aligned offsets (total ~236.0 MB).
    // X (h exchange, 257 slots x 128KB = 33,685,504 B) ALIASES the
    // emb/WP/WXT/WCT region [256, 33685760): those are all dead before
    // seed_h0/lstm_scan run (stream-ordered).
    const size_t OFF_X   = 256;
    const size_t OFF_EMB = 256;          // 20,480,000 B (emb bf16)
    const size_t OFF_WP  = 20480256;     //  2,097,152 B (W_proj bf16)
    const size_t OFF_WXT = 22577408;     //  8,388,608 B (W_x^T bf16, 4096x1024)
    const size_t OFF_WCT = 30966016;     //  8,388,608 B (Wc^T bf16, 4096x1024)
    const size_t OFF_WHF = 39354624;     //  8,388,608 B (W_h frag-order bf16)
    const size_t OFF_WOT = 47743232;     // 20,480,000 B (W_out^T bf16, 10000x1024)
    const size_t OFF_BC  = 68223232;     //     16,384 B (bc f32)
    const size_t OFF_XG  = 68239616;     // 134,217,728 B (xg bf16, 16384x4096)
    const size_t OFF_RES = 202457344;    // 33,554,432 B (res bf16, 16384x1024)
    const size_t OFF_PROG= 236011776;    //      1,024 B (progress flags)

    unsigned short* Xbuf   = (unsigned short*)(ws + OFF_X);
    unsigned short* emb_bf = (unsigned short*)(ws + OFF_EMB);
    unsigned short* Wp_bf  = (unsigned short*)(ws + OFF_WP);
    unsigned short* WxT    = (unsigned short*)(ws + OFF_WXT);
    unsigned short* WcT    = (unsigned short*)(ws + OFF_WCT);
    unsigned short* Whf    = (unsigned short*)(ws + OFF_WHF);
    unsigned short* WoT    = (unsigned short*)(ws + OFF_WOT);
    float*          bc     = (float*)(ws + OFF_BC);
    unsigned short* xg     = (unsigned short*)(ws + OFF_XG);
    unsigned short* resb   = (unsigned short*)(ws + OFF_RES);
    unsigned int*   prog   = (unsigned int*)(ws + OFF_PROG);

    hipMemsetAsync(prog, 0, 1024, stream);

    cvt_bf16<<<40000, 256, 0, stream>>>(emb, emb_bf, 10240000);
    cvt_bf16<<<4096, 256, 0, stream>>>(Wproj, Wp_bf, 1048576);
    transpose_cvt<<<dim3(64, 16), 256, 0, stream>>>(Wx, WxT, 1024, 4096);
    transpose_cvt<<<dim3(157, 16), 256, 0, stream>>>(Wout, WoT, 1024, 10000);
    whf_build<<<2048, 256, 0, stream>>>(Wh, Whf);
    bc_build<<<16, 256, 0, stream>>>(bproj, Wx, blstm, bc);

    // Wc^T = (W_proj @ W_x)^T   (bf16, transposed store)
    gemm_bt<2, false><<<dim3(32, 8), 256, 0, stream>>>(
        Wp_bf, WxT, (const int*)nullptr, (const float*)nullptr, WcT, 1024, 4096, 1024);

    // xg = emb[x] @ Wc + bc   (bf16 out)
    gemm_bt<1, true><<<dim3(32, 128), 256, 0, stream>>>(
        emb_bf, WcT, x, bc, xg, 16384, 4096, 4096);

    // h0 -> X slot 0 (exchange layout); runs after xg GEMM (X aliases emb/Wc)
    seed_h0<<<256, 256, 0, stream>>>(h0, Xbuf);

    // sequential LSTM scan (persistent, 1 block/CU, dataflow flags)
    lstm_scan<<<256, 256, 0, stream>>>(Whf, xg, c0, Xbuf, resb,
                                       out + 163840000, out + 163905536, prog);

    // out = res @ W_out + b_out  (f32 to d_out)
    gemm_bt<0, false><<<dim3(79, 128), 256, 0, stream>>>(
        resb, WoT, (const int*)nullptr, bout, d_out, 16384, 10000, 10000);
}